// Round 13
// baseline (530.530 us; speedup 1.0000x reference)
//
#include <hip/hip_runtime.h>
#include <hip/hip_bf16.h>
#include <math.h>

// Problem constants (N_WAY=64, K_SHOT=5, Q_QUERY=128, D_FEAT=128)
#define M     8192      // n*q query rows
#define D     128       // feature dim
#define NCLS  64        // n classes
#define KSHOT 5
#define XROW  133       // (k+q) rows per class in x
#define KTOP  9
#define EPSV  1e-8f

// Threshold filter: sims ~ N(0, 1/128), 9th-of-8192 ~ 0.27. bf16-input dot
// error eps <= 2^-8 * ||a||*||b|| <= 0.004. Count at TAU_HI, include at
// TAU_LO = TAU_HI - 0.01 >= 2*eps margin. cnt_hi>=9 => candidate set provably
// contains the exact top-9 (see proof in round notes); else exact fallback.
#define TAU_HI 0.24f
#define TAU_LO 0.23f
#define CAP    64       // candidate list capacity per row (expected ~27)

// k2f: MFMA filter pass. Block = 64 i (4 waves x 16-i subs) x 512 j (SJ=16).
#define SJ    16
#define JPB   (M / SJ)      // 512 j per block
#define NTIL  (JPB / 16)    // 32 j-tiles of 16

typedef __attribute__((__ext_vector_type__(8))) short bf16v8;  // 8 bf16 = 4 VGPR
typedef __attribute__((__ext_vector_type__(4))) float f32v4;

// ---------------------------------------------------------------------------
// register-resident top-K with (value desc, index asc) tie-break, matching
// jax.lax.top_k set semantics; arrival-order independent for distinct indices.
template <int KN>
__device__ __forceinline__ void topk_insert(float (&kv)[KN], int (&ki)[KN],
                                            float v, int j) {
  if (v > kv[KN - 1] || (v == kv[KN - 1] && j < ki[KN - 1])) {
    float cv = v; int cj = j;
#pragma unroll
    for (int t = 0; t < KN; ++t) {
      bool b = (cv > kv[t]) || (cv == kv[t] && cj < ki[t]);
      float tv = kv[t]; int ti_ = ki[t];
      kv[t] = b ? cv : tv;  ki[t] = b ? cj : ti_;
      cv   = b ? tv : cv;   cj   = b ? ti_ : cj;
    }
  }
}

// ---------------------------------------------------------------------------
__global__ void k0_proto(const float* __restrict__ x, float* __restrict__ protnT) {
  int c = blockIdx.x;
  int lane = threadIdx.x;
  const float* base = x + (size_t)(c * XROW) * D;
  float a0 = 0.f, a1 = 0.f;
#pragma unroll
  for (int s = 0; s < KSHOT; ++s) {
    a0 += base[s * D + lane];
    a1 += base[s * D + 64 + lane];
  }
  a0 *= 0.2f; a1 *= 0.2f;
  float ss = a0 * a0 + a1 * a1;
#pragma unroll
  for (int off = 1; off < 64; off <<= 1) ss += __shfl_xor(ss, off);
  float rn = 1.0f / fmaxf(sqrtf(ss), EPSV);
  protnT[lane * NCLS + c]        = a0 * rn;
  protnT[(lane + 64) * NCLS + c] = a1 * rn;
}

// ---------------------------------------------------------------------------
// k1: L2-normalize query rows -> qn (f32) and qh (bf16).
__global__ void k1_qnorm(const float* __restrict__ x, float* __restrict__ qn,
                         short* __restrict__ qh) {
  int lane = threadIdx.x & 63;
  int wv = threadIdx.x >> 6;
  int r = blockIdx.x * 4 + wv;
  int xr = (r >> 7) * XROW + KSHOT + (r & 127);
  const float* src = x + (size_t)xr * D;
  float v0 = src[lane], v1 = src[64 + lane];
  float ss = v0 * v0 + v1 * v1;
#pragma unroll
  for (int off = 1; off < 64; off <<= 1) ss += __shfl_xor(ss, off);
  float rn = 1.0f / fmaxf(sqrtf(ss), EPSV);
  float q0 = v0 * rn, q1 = v1 * rn;
  qn[(size_t)r * D + lane]      = q0;
  qn[(size_t)r * D + 64 + lane] = q1;
  __hip_bfloat16 h0 = __float2bfloat16(q0);
  __hip_bfloat16 h1 = __float2bfloat16(q1);
  qh[(size_t)r * D + lane]      = *(short*)&h0;
  qh[(size_t)r * D + 64 + lane] = *(short*)&h1;
}

// ---------------------------------------------------------------------------
// k2f: bf16 MFMA + threshold filter. No in-loop top-k (R9-R11 lesson: per-wave
// lists trigger the insert body ~every tile -> VALU-bound at 325us).
// D layout (m89-verified): i-col = lane&15, j-row = (lane>>4)*4 + reg.
__global__ __launch_bounds__(256) void
k2f(const short* __restrict__ qh, int* __restrict__ cnt, int* __restrict__ cnthi,
    int* __restrict__ cand) {
  __shared__ __align__(16) short jh[2][16 * D];   // 2 x 4 KB j-tile

  const int tid  = threadIdx.x;
  const int l    = tid & 63;
  const int w    = tid >> 6;
  const int ib   = blockIdx.x >> 4;        // 128 i-strips of 64
  const int js   = blockIdx.x & (SJ - 1);  // 16 j-splits
  const int i0   = ib * 64;
  const int j0s  = js * JPB;

  const bf16v8* qh8 = (const bf16v8*)qh;

  // persistent i-side B fragments: lane's i-row, 4 k-windows
  const int irow = i0 + w * 16 + (l & 15);
  const int lg   = l >> 4;                 // k-group 0..3
  bf16v8 bh[4];
#pragma unroll
  for (int kk = 0; kk < 4; ++kk)
    bh[kk] = qh8[(size_t)irow * 16 + kk * 4 + lg];

  // stage indexing: thread t -> (row, chunk); XOR-swizzle chunk by row&7
  const int srow = tid >> 4;               // 0..15
  const int schk = tid & 15;               // 0..15
  const int sslot = srow * 16 + (schk ^ (srow & 7));
  const int arow = l & 15;                 // A-frag j-row within tile
  int rslot[4];
#pragma unroll
  for (int kk = 0; kk < 4; ++kk)
    rslot[kk] = arow * 16 + ((kk * 4 + lg) ^ (arow & 7));

  const int myi = i0 + w * 16 + (l & 15);  // this lane's i-row

  // prologue: tile 0 -> buf0; prefetch tile 1 to regs
  bf16v8 sa = qh8[(size_t)(j0s + srow) * 16 + schk];
  ((bf16v8*)jh[0])[sslot] = sa;
  sa = qh8[(size_t)(j0s + 16 + srow) * 16 + schk];
  __syncthreads();

  for (int t = 0; t < NTIL; ++t) {
    if (t + 1 < NTIL) {
      ((bf16v8*)jh[(t + 1) & 1])[sslot] = sa;
      if (t + 2 < NTIL)
        sa = qh8[(size_t)(j0s + (t + 2) * 16 + srow) * 16 + schk];
    }

    const bf16v8* H = (const bf16v8*)jh[t & 1];
    f32v4 a0 = {0.f, 0.f, 0.f, 0.f};
    f32v4 a1 = {0.f, 0.f, 0.f, 0.f};
    a0 = __builtin_amdgcn_mfma_f32_16x16x32_bf16(H[rslot[0]], bh[0], a0, 0, 0, 0);
    a1 = __builtin_amdgcn_mfma_f32_16x16x32_bf16(H[rslot[1]], bh[1], a1, 0, 0, 0);
    a0 = __builtin_amdgcn_mfma_f32_16x16x32_bf16(H[rslot[2]], bh[2], a0, 0, 0, 0);
    a1 = __builtin_amdgcn_mfma_f32_16x16x32_bf16(H[rslot[3]], bh[3], a1, 0, 0, 0);
    f32v4 s = a0 + a1;

    const int jb = j0s + t * 16 + lg * 4;  // lane's 4 j-rows
#pragma unroll
    for (int u = 0; u < 4; ++u) {
      float v = s[u];
      if (v >= TAU_LO) {                   // rare (~0.5% of values)
        int slot = atomicAdd(&cnt[myi], 1);
        if (slot < CAP) cand[(size_t)myi * CAP + slot] = jb + u;
        if (v > TAU_HI) atomicAdd(&cnthi[myi], 1);
      }
    }
    __syncthreads();
  }
}

// ---------------------------------------------------------------------------
// k_rerank: rows with cnt_hi>=9 and no overflow: exact fp32 dots for all
// candidates, exact top-9 (jax tie-break). One wave per row, cooperative dot.
__global__ void k_rerank(const float* __restrict__ qn, const int* __restrict__ cnt,
                         const int* __restrict__ cnthi, const int* __restrict__ cand,
                         float* __restrict__ kval, int* __restrict__ kidx) {
  int lane = threadIdx.x & 63;
  int wv   = threadIdx.x >> 6;
  int i = blockIdx.x * 4 + wv;
  int c = cnt[i], chi = cnthi[i];
  if (chi < KTOP || c > CAP) return;       // fallback kernel owns this row
  float qi0 = qn[(size_t)i * D + lane];
  float qi1 = qn[(size_t)i * D + 64 + lane];
  float kv[KTOP]; int ki[KTOP];
#pragma unroll
  for (int t = 0; t < KTOP; ++t) { kv[t] = -INFINITY; ki[t] = 0x7fffffff; }
  for (int t = 0; t < c; ++t) {
    int jc = cand[(size_t)i * CAP + t];    // wave-uniform
    float p = qi0 * qn[(size_t)jc * D + lane] + qi1 * qn[(size_t)jc * D + 64 + lane];
#pragma unroll
    for (int off = 1; off < 64; off <<= 1) p += __shfl_xor(p, off);
    topk_insert<KTOP>(kv, ki, p, jc);      // wave-uniform branch
  }
  if (lane == 0) {
#pragma unroll
    for (int t = 0; t < KTOP; ++t) {
      kval[(size_t)i * KTOP + t] = kv[t];
      kidx[(size_t)i * KTOP + t] = ki[t];
    }
  }
}

// ---------------------------------------------------------------------------
// k_fb: exact fp32 full-row top-9 for rows the filter couldn't certify
// (cnt_hi<9 or overflow). Expected ~0 rows; correctness backstop.
__global__ void k_fb(const float* __restrict__ qn, const int* __restrict__ cnt,
                     const int* __restrict__ cnthi,
                     float* __restrict__ kval, int* __restrict__ kidx) {
  __shared__ float qi_s[4][D];
  int lane = threadIdx.x & 63;
  int wv   = threadIdx.x >> 6;
  int i = blockIdx.x * 4 + wv;
  int c = cnt[i], chi = cnthi[i];
  if (chi >= KTOP && c <= CAP) return;     // rerank handled it
  qi_s[wv][lane]      = qn[(size_t)i * D + lane];
  qi_s[wv][64 + lane] = qn[(size_t)i * D + 64 + lane];
  float kv[KTOP]; int ki[KTOP];
#pragma unroll
  for (int t = 0; t < KTOP; ++t) { kv[t] = -INFINITY; ki[t] = 0x7fffffff; }
  const float4* qi4 = (const float4*)qi_s[wv];
  for (int jb = 0; jb < M; jb += 64) {
    int j = jb + lane;
    const float4* qj = (const float4*)(qn + (size_t)j * D);
    float dot = 0.f;
#pragma unroll 8
    for (int ch = 0; ch < 32; ++ch) {
      float4 a = qi4[ch], b = qj[ch];
      dot += a.x * b.x + a.y * b.y + a.z * b.z + a.w * b.w;
    }
    topk_insert<KTOP>(kv, ki, dot, j);
  }
  // butterfly all-reduce merge of per-lane top-9 lists
#pragma unroll
  for (int off = 1; off < 64; off <<= 1) {
    float pv[KTOP]; int pj[KTOP];
#pragma unroll
    for (int t = 0; t < KTOP; ++t) {
      pv[t] = __shfl_xor(kv[t], off);
      pj[t] = __shfl_xor(ki[t], off);
    }
#pragma unroll
    for (int t = 0; t < KTOP; ++t) topk_insert<KTOP>(kv, ki, pv[t], pj[t]);
  }
  if (lane == 0) {
#pragma unroll
    for (int t = 0; t < KTOP; ++t) {
      kval[(size_t)i * KTOP + t] = kv[t];
      kidx[(size_t)i * KTOP + t] = ki[t];
    }
  }
}

// ---------------------------------------------------------------------------
// k3: mutual mask + softmax over <=9 entries + adapted query + normalize +
// project on normalized prototypes, scale by tao. One wave per query row.
__global__ void k3_out(const float* __restrict__ x, const float* __restrict__ kval,
                       const int* __restrict__ kidx, const float* __restrict__ protnT,
                       const float* __restrict__ taop, float* __restrict__ out) {
  __shared__ float sw[4][KTOP];
  __shared__ int   sj[4][KTOP];
  __shared__ float an[4][D];
  int lane = threadIdx.x & 63;
  int wv   = threadIdx.x >> 6;
  int i = blockIdx.x * 4 + wv;

  float v = -INFINITY; int jt = 0; bool mut = false;
  if (lane < KTOP) {
    v  = kval[(size_t)i * KTOP + lane];
    jt = kidx[(size_t)i * KTOP + lane];
    const int* oj = kidx + (size_t)jt * KTOP;
#pragma unroll
    for (int t = 0; t < KTOP; ++t) mut = mut || (oj[t] == i);
  }
  float lv = mut ? v : -INFINITY;
#pragma unroll
  for (int off = 1; off < 16; off <<= 1) lv = fmaxf(lv, __shfl_xor(lv, off));
  float wexp = mut ? expf(v - lv) : 0.f;    // self is always mutual -> z >= 1
  float z = wexp;
#pragma unroll
  for (int off = 1; off < 16; off <<= 1) z += __shfl_xor(z, off);
  if (lane < KTOP) { sw[wv][lane] = wexp / z; sj[wv][lane] = jt; }
  __syncthreads();

  float a0 = 0.f, a1 = 0.f;
#pragma unroll
  for (int t = 0; t < KTOP; ++t) {
    float wt = sw[wv][t];
    if (wt != 0.f) {
      int j = sj[wv][t];
      int xr = (j >> 7) * XROW + KSHOT + (j & 127);
      const float* qr = x + (size_t)xr * D;
      a0 += wt * qr[lane];
      a1 += wt * qr[64 + lane];
    }
  }
  float ss = a0 * a0 + a1 * a1;
#pragma unroll
  for (int off = 1; off < 64; off <<= 1) ss += __shfl_xor(ss, off);
  float rn = 1.0f / fmaxf(sqrtf(ss), EPSV);
  an[wv][lane]      = a0 * rn;
  an[wv][64 + lane] = a1 * rn;
  __syncthreads();

  float acc = 0.f;
#pragma unroll 8
  for (int d = 0; d < D; ++d) acc += an[wv][d] * protnT[d * NCLS + lane];
  out[(size_t)i * NCLS + lane] = taop[0] * acc;
}

// ---------------------------------------------------------------------------
extern "C" void kernel_launch(void* const* d_in, const int* in_sizes, int n_in,
                              void* d_out, int out_size, void* d_ws, size_t ws_size,
                              hipStream_t stream) {
  const float* x   = (const float*)d_in[0];
  const float* tao = (const float*)d_in[1];
  float* out = (float*)d_out;

  // workspace layout, ~8.8 MB total
  float* qn   = (float*)d_ws;                         // 8192*128 f32 (4 MB)
  short* qh   = (short*)(qn + (size_t)M * D);         // 2 MB bf16
  int*   cnt  = (int*)(qh + (size_t)M * D);           // 32 KB
  int*   cnthi= cnt + M;                              // 32 KB (contiguous w/ cnt)
  int*   cand = cnthi + M;                            // 8192*64*4 = 2 MB
  float* kval = (float*)(cand + (size_t)M * CAP);     // 8192*9
  int*   kidx = (int*)(kval + (size_t)M * KTOP);
  float* protnT = (float*)(kidx + (size_t)M * KTOP);  // 128*64

  hipMemsetAsync(cnt, 0, 2 * (size_t)M * sizeof(int), stream);
  k0_proto<<<NCLS, 64, 0, stream>>>(x, protnT);
  k1_qnorm<<<M / 4, 256, 0, stream>>>(x, qn, qh);
  k2f<<<(M / 64) * SJ, 256, 0, stream>>>(qh, cnt, cnthi, cand);
  k_rerank<<<M / 4, 256, 0, stream>>>(qn, cnt, cnthi, cand, kval, kidx);
  k_fb<<<M / 4, 256, 0, stream>>>(qn, cnt, cnthi, kval, kidx);
  k3_out<<<M / 4, 256, 0, stream>>>(x, kval, kidx, protnT, tao, out);
}

// Round 14
// 243.642 us; speedup vs baseline: 2.1775x; 2.1775x over previous
//
#include <hip/hip_runtime.h>
#include <hip/hip_bf16.h>
#include <math.h>

// Problem constants (N_WAY=64, K_SHOT=5, Q_QUERY=128, D_FEAT=128)
#define M     8192      // n*q query rows
#define D     128       // feature dim
#define NCLS  64        // n classes
#define KSHOT 5
#define XROW  133       // (k+q) rows per class in x
#define KTOP  9
#define EPSV  1e-8f

// Threshold filter + exact certificate:
//   sims ~ N(0,1/128) (sigma .088); exact 9th-of-row ~ 0.27.
//   bf16-input MFMA dot error <= 2^-8*||a||*||b|| + accum ~ 0.004 < EPS_DOT.
//   k2f appends j with approx >= TAU_LO. k_rerank computes EXACT fp32 dots of
//   all candidates and certifies iff exact-9th-among-candidates > TAU_LO+EPS_DOT
//   (then true top-9 provably subset of candidates). Cert failure needs the
//   row's exact 9th < 0.215: Poisson(61) P(<9) ~ 1e-13/row. k_fb backstop.
//   R12 lesson: cnt_hi certificate had P(fail) ~ 1e-4/row -> 1-2 rows hit the
//   447us serial fallback. Margin matters more than the fallback's speed.
#define TAU_LO  0.21f
#define EPS_DOT 0.005f
#define CAP     160     // candidate capacity (mean ~72, overflow P~1e-20)

// k2f: MFMA filter pass. Block = 64 i (4 waves x 16-i subs) x 512 j (SJ=16).
// No LDS, no barriers: A-frags loaded straight from global (L2-resident qh).
#define SJ    16
#define JPB   (M / SJ)      // 512 j per block
#define NTIL  (JPB / 16)    // 32 j-tiles of 16

typedef __attribute__((__ext_vector_type__(8))) short bf16v8;  // 8 bf16 = 4 VGPR
typedef __attribute__((__ext_vector_type__(4))) float f32v4;

// ---------------------------------------------------------------------------
// register-resident top-K with (value desc, index asc) tie-break, matching
// jax.lax.top_k set semantics; arrival-order independent for distinct indices.
template <int KN>
__device__ __forceinline__ void topk_insert(float (&kv)[KN], int (&ki)[KN],
                                            float v, int j) {
  if (v > kv[KN - 1] || (v == kv[KN - 1] && j < ki[KN - 1])) {
    float cv = v; int cj = j;
#pragma unroll
    for (int t = 0; t < KN; ++t) {
      bool b = (cv > kv[t]) || (cv == kv[t] && cj < ki[t]);
      float tv = kv[t]; int ti_ = ki[t];
      kv[t] = b ? cv : tv;  ki[t] = b ? cj : ti_;
      cv   = b ? tv : cv;   cj   = b ? ti_ : cj;
    }
  }
}

// ---------------------------------------------------------------------------
__global__ void k0_proto(const float* __restrict__ x, float* __restrict__ protnT) {
  int c = blockIdx.x;
  int lane = threadIdx.x;
  const float* base = x + (size_t)(c * XROW) * D;
  float a0 = 0.f, a1 = 0.f;
#pragma unroll
  for (int s = 0; s < KSHOT; ++s) {
    a0 += base[s * D + lane];
    a1 += base[s * D + 64 + lane];
  }
  a0 *= 0.2f; a1 *= 0.2f;
  float ss = a0 * a0 + a1 * a1;
#pragma unroll
  for (int off = 1; off < 64; off <<= 1) ss += __shfl_xor(ss, off);
  float rn = 1.0f / fmaxf(sqrtf(ss), EPSV);
  protnT[lane * NCLS + c]        = a0 * rn;
  protnT[(lane + 64) * NCLS + c] = a1 * rn;
}

// ---------------------------------------------------------------------------
// k1: L2-normalize query rows -> qn (f32) and qh (bf16).
__global__ void k1_qnorm(const float* __restrict__ x, float* __restrict__ qn,
                         short* __restrict__ qh) {
  int lane = threadIdx.x & 63;
  int wv = threadIdx.x >> 6;
  int r = blockIdx.x * 4 + wv;
  int xr = (r >> 7) * XROW + KSHOT + (r & 127);
  const float* src = x + (size_t)xr * D;
  float v0 = src[lane], v1 = src[64 + lane];
  float ss = v0 * v0 + v1 * v1;
#pragma unroll
  for (int off = 1; off < 64; off <<= 1) ss += __shfl_xor(ss, off);
  float rn = 1.0f / fmaxf(sqrtf(ss), EPSV);
  float q0 = v0 * rn, q1 = v1 * rn;
  qn[(size_t)r * D + lane]      = q0;
  qn[(size_t)r * D + 64 + lane] = q1;
  __hip_bfloat16 h0 = __float2bfloat16(q0);
  __hip_bfloat16 h1 = __float2bfloat16(q1);
  qh[(size_t)r * D + lane]      = *(short*)&h0;
  qh[(size_t)r * D + 64 + lane] = *(short*)&h1;
}

// ---------------------------------------------------------------------------
// k2f: bf16 MFMA + threshold filter, barrier-free (no LDS).
// D layout (m89-verified): i-col = lane&15, j-row = (lane>>4)*4 + reg.
__global__ __launch_bounds__(256) void
k2f(const short* __restrict__ qh, int* __restrict__ cnt, int* __restrict__ cand) {
  const int tid  = threadIdx.x;
  const int l    = tid & 63;
  const int w    = tid >> 6;
  const int ib   = blockIdx.x >> 4;        // 128 i-strips of 64
  const int js   = blockIdx.x & (SJ - 1);  // 16 j-splits
  const int i0   = ib * 64;
  const int j0s  = js * JPB;

  const bf16v8* qh8 = (const bf16v8*)qh;
  const int lg   = l >> 4;                 // k-group 0..3
  const int arow = l & 15;
  const int myi  = i0 + w * 16 + arow;     // this lane's i-row

  // persistent i-side B fragments: lane's i-row, 4 k-windows
  bf16v8 bh[4];
#pragma unroll
  for (int kk = 0; kk < 4; ++kk)
    bh[kk] = qh8[(size_t)myi * 16 + kk * 4 + lg];

  for (int t = 0; t < NTIL; ++t) {
    const size_t jr16 = (size_t)(j0s + t * 16 + arow) * 16;
    bf16v8 ah0 = qh8[jr16 + 0 + lg];
    bf16v8 ah1 = qh8[jr16 + 4 + lg];
    bf16v8 ah2 = qh8[jr16 + 8 + lg];
    bf16v8 ah3 = qh8[jr16 + 12 + lg];
    f32v4 a0 = {0.f, 0.f, 0.f, 0.f};
    f32v4 a1 = {0.f, 0.f, 0.f, 0.f};
    a0 = __builtin_amdgcn_mfma_f32_16x16x32_bf16(ah0, bh[0], a0, 0, 0, 0);
    a1 = __builtin_amdgcn_mfma_f32_16x16x32_bf16(ah1, bh[1], a1, 0, 0, 0);
    a0 = __builtin_amdgcn_mfma_f32_16x16x32_bf16(ah2, bh[2], a0, 0, 0, 0);
    a1 = __builtin_amdgcn_mfma_f32_16x16x32_bf16(ah3, bh[3], a1, 0, 0, 0);
    f32v4 s = a0 + a1;

    const int jb = j0s + t * 16 + lg * 4;  // lane's 4 j-rows
#pragma unroll
    for (int u = 0; u < 4; ++u) {
      if (s[u] >= TAU_LO) {                // ~0.9% of values
        int slot = atomicAdd(&cnt[myi], 1);
        if (slot < CAP) cand[(size_t)myi * CAP + slot] = jb + u;
      }
    }
  }
}

// ---------------------------------------------------------------------------
// k_rerank: exact fp32 dots for all candidates; exact top-9 (jax tie-break);
// certify exact-9th > TAU_LO + EPS_DOT, clear fbflag on success.
__global__ void k_rerank(const float* __restrict__ qn, const int* __restrict__ cnt,
                         const int* __restrict__ cand, int* __restrict__ fbflag,
                         float* __restrict__ kval, int* __restrict__ kidx) {
  int lane = threadIdx.x & 63;
  int wv   = threadIdx.x >> 6;
  int i = blockIdx.x * 4 + wv;
  int c = cnt[i];
  if (c < KTOP || c > CAP) return;         // fbflag stays set -> k_fb owns row
  float qi0 = qn[(size_t)i * D + lane];
  float qi1 = qn[(size_t)i * D + 64 + lane];
  float kv[KTOP]; int ki[KTOP];
#pragma unroll
  for (int t = 0; t < KTOP; ++t) { kv[t] = -INFINITY; ki[t] = 0x7fffffff; }
  for (int t = 0; t < c; ++t) {
    int jc = cand[(size_t)i * CAP + t];    // wave-uniform
    float p = qi0 * qn[(size_t)jc * D + lane] + qi1 * qn[(size_t)jc * D + 64 + lane];
#pragma unroll
    for (int off = 1; off < 64; off <<= 1) p += __shfl_xor(p, off);
    topk_insert<KTOP>(kv, ki, p, jc);      // wave-uniform branch
  }
  if (kv[KTOP - 1] <= TAU_LO + EPS_DOT) return;   // cert fail -> k_fb
  if (lane == 0) {
    fbflag[i] = 0;
#pragma unroll
    for (int t = 0; t < KTOP; ++t) {
      kval[(size_t)i * KTOP + t] = kv[t];
      kidx[(size_t)i * KTOP + t] = ki[t];
    }
  }
}

// ---------------------------------------------------------------------------
// k_fb: exact fp32 full-row top-9 backstop (P ~ 1e-13 per row).
__global__ void k_fb(const float* __restrict__ qn, const int* __restrict__ fbflag,
                     float* __restrict__ kval, int* __restrict__ kidx) {
  __shared__ float qi_s[4][D];
  int lane = threadIdx.x & 63;
  int wv   = threadIdx.x >> 6;
  int i = blockIdx.x * 4 + wv;
  if (fbflag[i] == 0) return;              // rerank certified it
  qi_s[wv][lane]      = qn[(size_t)i * D + lane];
  qi_s[wv][64 + lane] = qn[(size_t)i * D + 64 + lane];
  float kv[KTOP]; int ki[KTOP];
#pragma unroll
  for (int t = 0; t < KTOP; ++t) { kv[t] = -INFINITY; ki[t] = 0x7fffffff; }
  const float4* qi4 = (const float4*)qi_s[wv];
  for (int jb = 0; jb < M; jb += 64) {
    int j = jb + lane;
    const float4* qj = (const float4*)(qn + (size_t)j * D);
    float dot = 0.f;
#pragma unroll 8
    for (int ch = 0; ch < 32; ++ch) {
      float4 a = qi4[ch], b = qj[ch];
      dot += a.x * b.x + a.y * b.y + a.z * b.z + a.w * b.w;
    }
    topk_insert<KTOP>(kv, ki, dot, j);
  }
#pragma unroll
  for (int off = 1; off < 64; off <<= 1) {
    float pv[KTOP]; int pj[KTOP];
#pragma unroll
    for (int t = 0; t < KTOP; ++t) {
      pv[t] = __shfl_xor(kv[t], off);
      pj[t] = __shfl_xor(ki[t], off);
    }
#pragma unroll
    for (int t = 0; t < KTOP; ++t) topk_insert<KTOP>(kv, ki, pv[t], pj[t]);
  }
  if (lane == 0) {
#pragma unroll
    for (int t = 0; t < KTOP; ++t) {
      kval[(size_t)i * KTOP + t] = kv[t];
      kidx[(size_t)i * KTOP + t] = ki[t];
    }
  }
}

// ---------------------------------------------------------------------------
// k3: mutual mask + softmax over <=9 entries + adapted query + normalize +
// project on normalized prototypes, scale by tao. One wave per query row.
__global__ void k3_out(const float* __restrict__ x, const float* __restrict__ kval,
                       const int* __restrict__ kidx, const float* __restrict__ protnT,
                       const float* __restrict__ taop, float* __restrict__ out) {
  __shared__ float sw[4][KTOP];
  __shared__ int   sj[4][KTOP];
  __shared__ float an[4][D];
  int lane = threadIdx.x & 63;
  int wv   = threadIdx.x >> 6;
  int i = blockIdx.x * 4 + wv;

  float v = -INFINITY; int jt = 0; bool mut = false;
  if (lane < KTOP) {
    v  = kval[(size_t)i * KTOP + lane];
    jt = kidx[(size_t)i * KTOP + lane];
    const int* oj = kidx + (size_t)jt * KTOP;
#pragma unroll
    for (int t = 0; t < KTOP; ++t) mut = mut || (oj[t] == i);
  }
  float lv = mut ? v : -INFINITY;
#pragma unroll
  for (int off = 1; off < 16; off <<= 1) lv = fmaxf(lv, __shfl_xor(lv, off));
  float wexp = mut ? expf(v - lv) : 0.f;    // self is always mutual -> z >= 1
  float z = wexp;
#pragma unroll
  for (int off = 1; off < 16; off <<= 1) z += __shfl_xor(z, off);
  if (lane < KTOP) { sw[wv][lane] = wexp / z; sj[wv][lane] = jt; }
  __syncthreads();

  float a0 = 0.f, a1 = 0.f;
#pragma unroll
  for (int t = 0; t < KTOP; ++t) {
    float wt = sw[wv][t];
    if (wt != 0.f) {
      int j = sj[wv][t];
      int xr = (j >> 7) * XROW + KSHOT + (j & 127);
      const float* qr = x + (size_t)xr * D;
      a0 += wt * qr[lane];
      a1 += wt * qr[64 + lane];
    }
  }
  float ss = a0 * a0 + a1 * a1;
#pragma unroll
  for (int off = 1; off < 64; off <<= 1) ss += __shfl_xor(ss, off);
  float rn = 1.0f / fmaxf(sqrtf(ss), EPSV);
  an[wv][lane]      = a0 * rn;
  an[wv][64 + lane] = a1 * rn;
  __syncthreads();

  float acc = 0.f;
#pragma unroll 8
  for (int d = 0; d < D; ++d) acc += an[wv][d] * protnT[d * NCLS + lane];
  out[(size_t)i * NCLS + lane] = taop[0] * acc;
}

// ---------------------------------------------------------------------------
extern "C" void kernel_launch(void* const* d_in, const int* in_sizes, int n_in,
                              void* d_out, int out_size, void* d_ws, size_t ws_size,
                              hipStream_t stream) {
  const float* x   = (const float*)d_in[0];
  const float* tao = (const float*)d_in[1];
  float* out = (float*)d_out;

  // workspace layout, ~11.8 MB total
  float* qn    = (float*)d_ws;                        // 8192*128 f32 (4 MB)
  short* qh    = (short*)(qn + (size_t)M * D);        // 2 MB bf16
  int*   cnt   = (int*)(qh + (size_t)M * D);          // 32 KB
  int*   fbflag= cnt + M;                             // 32 KB
  int*   cand  = fbflag + M;                          // 8192*160*4 = 5.2 MB
  float* kval  = (float*)(cand + (size_t)M * CAP);    // 8192*9
  int*   kidx  = (int*)(kval + (size_t)M * KTOP);
  float* protnT = (float*)(kidx + (size_t)M * KTOP);  // 128*64

  hipMemsetAsync(cnt, 0, (size_t)M * sizeof(int), stream);
  hipMemsetAsync(fbflag, 0xFF, (size_t)M * sizeof(int), stream);
  k0_proto<<<NCLS, 64, 0, stream>>>(x, protnT);
  k1_qnorm<<<M / 4, 256, 0, stream>>>(x, qn, qh);
  k2f<<<(M / 64) * SJ, 256, 0, stream>>>(qh, cnt, cand);
  k_rerank<<<M / 4, 256, 0, stream>>>(qn, cnt, cand, fbflag, kval, kidx);
  k_fb<<<M / 4, 256, 0, stream>>>(qn, fbflag, kval, kidx);
  k3_out<<<M / 4, 256, 0, stream>>>(x, kval, kidx, protnT, tao, out);
}